// Round 22
// baseline (93.997 us; speedup 1.0000x reference)
//
#include <hip/hip_runtime.h>
#include <math.h>

typedef float f32x16 __attribute__((ext_vector_type(16)));
typedef short bf16x8 __attribute__((ext_vector_type(8)));
typedef short bf16x4 __attribute__((ext_vector_type(4)));
typedef unsigned short u16;
typedef unsigned int u32;

#define MFMA32(a, b, c) __builtin_amdgcn_mfma_f32_32x32x16_bf16(a, b, c, 0, 0, 0)

__device__ __forceinline__ u16 f2bf(float x) {
    u32 u = __float_as_uint(x);
    u += 0x7FFFu + ((u >> 16) & 1u);
    return (u16)(u >> 16);
}
__device__ __forceinline__ float bf2f(u16 h) {
    return __uint_as_float(((u32)h) << 16);
}
__device__ __forceinline__ void gload16(const void* g, void* l) {
    __builtin_amdgcn_global_load_lds(
        (const __attribute__((address_space(1))) unsigned int*)g,
        (__attribute__((address_space(3))) unsigned int*)l, 16, 0, 0);
}

// ---------------------------------------------------------------------------
// g_kernel (unchanged): 64x64 component-block matrices, bf16 hi/lo planes.
// ---------------------------------------------------------------------------
__global__ __launch_bounds__(256) void g_kernel(
    const float* __restrict__ Wq, const float* __restrict__ Wk,
    const float* __restrict__ Wv,
    u16* __restrict__ gmh, u16* __restrict__ gml,
    u16* __restrict__ mvh, u16* __restrict__ mvl)
{
    const int bk = blockIdx.x;
    const int base = ((bk & 3) * 256 + threadIdx.x) * 4;
    if (bk < 4) {
#pragma unroll
        for (int i = 0; i < 4; ++i) {
            int e = base + i;
            int f = e >> 6, fp = e & 63;
            int c = f & 3, cp = fp & 3, j = f >> 2, jp = fp >> 2;
            float val = 0.f;
            if (c == cp) {
                float a0 = 0.f, a1 = 0.f;
#pragma unroll 8
                for (int ff = 0; ff < 32; ff += 2) {
                    a0 = fmaf(Wq[ff * 16 + j],       Wk[ff * 16 + jp],       a0);
                    a1 = fmaf(Wq[(ff + 1) * 16 + j], Wk[(ff + 1) * 16 + jp], a1);
                }
                val = (a0 + a1) * ((c == 0) ? 1.f : -1.f);
            }
            u16 h = f2bf(val);
            gmh[e] = h; gml[e] = f2bf(val - bf2f(h));
        }
    } else {
#pragma unroll
        for (int i = 0; i < 4; ++i) {
            int e = base + i;
            int f = e >> 6, fp = e & 63;
            float val = ((f & 3) == (fp & 3)) ? expf(Wv[(f >> 2) * 16 + (fp >> 2)]) : 0.f;
            u16 h = f2bf(val);
            mvh[e] = h; mvl[e] = f2bf(val - bf2f(h));
        }
    }
}

// ---------------------------------------------------------------------------
// prep v16 (unchanged): all-MFMA, zero LDS; q-side scale folds log2(e).
// ---------------------------------------------------------------------------
__global__ __launch_bounds__(256) void prep_kernel(
    const float* __restrict__ vectors, const float* __restrict__ scalars,
    const float* __restrict__ Wq_s, const float* __restrict__ bq_s,
    const float* __restrict__ Wk_s, const float* __restrict__ bk_s,
    const u16* __restrict__ gmh, const u16* __restrict__ gml,
    const u16* __restrict__ mvh, const u16* __restrict__ mvl,
    u16* __restrict__ qh, u16* __restrict__ ql,
    u16* __restrict__ kh, u16* __restrict__ kl,
    u16* __restrict__ vth)
{
    const int t = threadIdx.x;
    const int w = t >> 6;
    const int lane = t & 63;
    const int l31 = lane & 31, g = lane >> 5;
    const int b = blockIdx.x >> 5;
    const int n0 = (blockIdx.x & 31) << 5;
    const long tok0 = (long)b * 1024 + n0;
    const float SC2 = 0.07216878364870323f * 1.4426950408889634f;

    if (w == 1 || w == 2) {
        bf16x8 Ah[4], Al[4];
        const float* vrow = vectors + (tok0 + l31) * 64 + g * 8;
#pragma unroll
        for (int kk = 0; kk < 4; ++kk) {
            float4 x0 = *(const float4*)(vrow + kk * 16);
            float4 x1 = *(const float4*)(vrow + kk * 16 + 4);
            float nr0 = x0.x * x0.x - x0.y * x0.y - x0.z * x0.z - x0.w * x0.w;
            float iv0 = 1.0f / sqrtf(fmaxf(fabsf(nr0), 1e-5f));
            float nr1 = x1.x * x1.x - x1.y * x1.y - x1.z * x1.z - x1.w * x1.w;
            float iv1 = 1.0f / sqrtf(fmaxf(fabsf(nr1), 1e-5f));
            float xs[8] = {x0.x * iv0, x0.y * iv0, x0.z * iv0, x0.w * iv0,
                           x1.x * iv1, x1.y * iv1, x1.z * iv1, x1.w * iv1};
#pragma unroll
            for (int e = 0; e < 8; ++e) {
                u16 h = f2bf(xs[e]);
                Ah[kk][e] = (short)h;
                Al[kk][e] = (short)f2bf(xs[e] - bf2f(h));
            }
        }

        const u16* bhp = (w == 1) ? gmh : mvh;
        const u16* blp = (w == 1) ? gml : mvl;
#pragma unroll
        for (int tile = 0; tile < 2; ++tile) {
            const int fs = tile * 32 + l31;
            const u16* bh = bhp + fs * 64 + g * 8;
            const u16* bl = blp + fs * 64 + g * 8;
            f32x16 acc;
#pragma unroll
            for (int r = 0; r < 16; ++r) acc[r] = 0.f;
#pragma unroll
            for (int kk = 0; kk < 4; ++kk) {
                bf16x8 Bh = *(const bf16x8*)(bh + kk * 16);
                bf16x8 Bl = *(const bf16x8*)(bl + kk * 16);
                acc = MFMA32(Ah[kk], Bh, acc);
                acc = MFMA32(Al[kk], Bh, acc);
                acc = MFMA32(Ah[kk], Bl, acc);
            }
            if (w == 1) {
#pragma unroll
                for (int reg = 0; reg < 16; ++reg) {
                    int trow = (reg & 3) + 8 * (reg >> 2) + 4 * g;
                    float val = acc[reg];
                    u16 h = f2bf(val);
                    kh[(tok0 + trow) * 128 + fs] = h;
                    kl[(tok0 + trow) * 64 + fs] = f2bf(val - bf2f(h));
                }
            } else {
#pragma unroll
                for (int reg = 0; reg < 16; ++reg) {
                    int trow = (reg & 3) + 8 * (reg >> 2) + 4 * g;
                    vth[((long)b * 64 + fs) * 1024 + n0 + trow] = f2bf(acc[reg]);
                }
            }
        }
    } else {
        if (w == 0) {
            const float* vrow = vectors + (tok0 + l31) * 64 + g * 8;
#pragma unroll
            for (int kk = 0; kk < 4; ++kk) {
                float4 x0 = *(const float4*)(vrow + kk * 16);
                float4 x1 = *(const float4*)(vrow + kk * 16 + 4);
                float nr0 = x0.x * x0.x - x0.y * x0.y - x0.z * x0.z - x0.w * x0.w;
                float iv0 = SC2 / sqrtf(fmaxf(fabsf(nr0), 1e-5f));
                float nr1 = x1.x * x1.x - x1.y * x1.y - x1.z * x1.z - x1.w * x1.w;
                float iv1 = SC2 / sqrtf(fmaxf(fabsf(nr1), 1e-5f));
                float xs[8] = {x0.x * iv0, x0.y * iv0, x0.z * iv0, x0.w * iv0,
                               x1.x * iv1, x1.y * iv1, x1.z * iv1, x1.w * iv1};
                u16 hh[8], ll[8];
#pragma unroll
                for (int e = 0; e < 8; ++e) {
                    hh[e] = f2bf(xs[e]);
                    ll[e] = f2bf(xs[e] - bf2f(hh[e]));
                }
                *(int4*)(qh + (tok0 + l31) * 128 + kk * 16 + g * 8) = *(int4*)hh;
                *(int4*)(ql + (tok0 + l31) * 64 + kk * 16 + g * 8) = *(int4*)ll;
            }
        }
        const int isq = (w == 0);
        bf16x8 Ah[4];
        const float* xrow = scalars + (tok0 + l31) * 64 + g * 8;
#pragma unroll
        for (int kk = 0; kk < 4; ++kk) {
            float4 x0 = *(const float4*)(xrow + kk * 16);
            float4 x1 = *(const float4*)(xrow + kk * 16 + 4);
            float xs[8] = {x0.x, x0.y, x0.z, x0.w, x1.x, x1.y, x1.z, x1.w};
#pragma unroll
            for (int e = 0; e < 8; ++e) Ah[kk][e] = (short)f2bf(xs[e]);
        }
        const float sc = isq ? SC2 : 1.f;
        u16* oh = isq ? qh : kh;
#pragma unroll
        for (int ft = 0; ft < 2; ++ft) {
            const int fs = (ft << 5) + l31;
            const float* wrow = (isq ? Wq_s : Wk_s) + fs * 64 + g * 8;
            f32x16 acc;
#pragma unroll
            for (int r = 0; r < 16; ++r) acc[r] = 0.f;
#pragma unroll
            for (int kk = 0; kk < 4; ++kk) {
                float4 w0_ = *(const float4*)(wrow + kk * 16);
                float4 w1_ = *(const float4*)(wrow + kk * 16 + 4);
                float ws_[8] = {w0_.x, w0_.y, w0_.z, w0_.w, w1_.x, w1_.y, w1_.z, w1_.w};
                bf16x8 Bh;
#pragma unroll
                for (int e = 0; e < 8; ++e) Bh[e] = (short)f2bf(ws_[e]);
                acc = MFMA32(Ah[kk], Bh, acc);
            }
            const float bias = (isq ? bq_s : bk_s)[fs];
#pragma unroll
            for (int reg = 0; reg < 16; ++reg) {
                int trow = (reg & 3) + 8 * (reg >> 2) + 4 * g;
                oh[(tok0 + trow) * 128 + 64 + fs] = f2bf((acc[reg] + bias) * sc);
            }
        }
    }
}

// ---------------------------------------------------------------------------
// attn v22: r18 inner math, but pair-loop with 4 K/V buffers and ONE barrier
// per 2 iterations. All buffer writes (gload-K + ds_write-V) happen at pair
// top for the NEXT pair; the end-of-pair barrier orders write->read.
// LDS 68 KB -> 2 blocks/CU.
// ---------------------------------------------------------------------------
__global__ __launch_bounds__(256) void attn_kernel(
    const u16* __restrict__ qh, const u16* __restrict__ ql,
    const u16* __restrict__ kh, const u16* __restrict__ kl,
    const u16* __restrict__ vth, float* __restrict__ out)
{
    __shared__ u16 KH[4 * 32 * 128];   // 32 KB, 4 buffers (gload, linear rows)
    __shared__ u16 KL[4 * 32 * 64];    // 16 KB, 4 buffers
    __shared__ u16 VH[4 * 64 * 40];    // 20 KB, 4 buffers (ds_write, pitch 40)

    const int t = threadIdx.x;
    const int lane = t & 63;
    const int w = t >> 6;
    const int l31 = lane & 31, g = lane >> 5;

    const int bid = blockIdx.x;              // 0..511
    const int b = ((bid & 7) << 3) + (bid >> 6);
    const int qt = (bid >> 3) & 7;

    const int qi = qt * 128 + w * 32 + l31;
    const long qtok = (long)b * 1024 + qi;

    bf16x8 Qh[8], Qlv[4];
    {
        const u16* qhp = qh + qtok * 128 + g * 8;
        const u16* qlp = ql + qtok * 64 + g * 8;
#pragma unroll
        for (int c = 0; c < 8; ++c) Qh[c] = *(const bf16x8*)(qhp + c * 16);
#pragma unroll
        for (int c = 0; c < 4; ++c) Qlv[c] = *(const bf16x8*)(qlp + c * 16);
    }

    // K staging: pre-swizzled global sources, linear LDS dest
    const int r0 = 8 * w + (lane >> 4);
    const int r1 = r0 + 4;
    const int su0 = (lane & 15) ^ (r0 & 15);
    const int su1 = (lane & 15) ^ (r1 & 15);
    const u16* kh0 = kh + ((long)b * 1024 + r0) * 128 + su0 * 8;
    const u16* kh1 = kh + ((long)b * 1024 + r1) * 128 + su1 * 8;
    const int rl_ = 8 * w + (lane >> 3);
    const int sul = (lane & 7) ^ (rl_ & 7);
    const u16* kl0 = kl + ((long)b * 1024 + rl_) * 64 + sul * 8;

    // V staging: reg + ds_write, pitch 40
    const int vdv = t >> 2, vq4 = t & 3;
    const u16* vhg = vth + ((long)b * 64 + vdv) * 1024 + vq4 * 8;
    u16* vdst = VH + vdv * 40 + vq4 * 8;
    int4 rvA, rvB;

#define STAGEK(kt, bf) do { \
        gload16(kh0 + (long)(kt) * 128, KH + (bf) * 4096 + w * 1024); \
        gload16(kh1 + (long)(kt) * 128, KH + (bf) * 4096 + w * 1024 + 512); \
        gload16(kl0 + (long)(kt) * 64,  KL + (bf) * 2048 + w * 512); \
    } while (0)

    f32x16 o0, o1;
#pragma unroll
    for (int r = 0; r < 16; ++r) { o0[r] = 0.f; o1[r] = 0.f; }
    float m_run = -1e30f, l_run = 0.f;

    // ---- prologue: buffers 0,1 filled; V data for iters 2,3 in regs ----
    rvA = *(const int4*)(vhg);
    rvB = *(const int4*)(vhg + 32);
    STAGEK(0, 0);
    STAGEK(32, 1);
    *(int4*)(vdst) = rvA;
    *(int4*)(vdst + 2560) = rvB;
    rvA = *(const int4*)(vhg + 64);
    rvB = *(const int4*)(vhg + 96);
    __syncthreads();

    for (int p = 0; p < 16; ++p) {
        if (p < 15) {
            // write V buffers for next pair; issue K gloads for next pair
            *(int4*)(vdst + ((2 * p + 2) & 3) * 2560) = rvA;
            *(int4*)(vdst + ((2 * p + 3) & 3) * 2560) = rvB;
            STAGEK((2 * p + 2) * 32, (2 * p + 2) & 3);
            STAGEK((2 * p + 3) * 32, (2 * p + 3) & 3);
            if (p < 14) {
                rvA = *(const int4*)(vhg + (2 * p + 4) * 32);
                rvB = *(const int4*)(vhg + (2 * p + 5) * 32);
            }
        }

#pragma unroll
        for (int h = 0; h < 2; ++h) {
            const int it = 2 * p + h;
            const int cb = it & 3;

            // ---- QK^T: 2 accumulator chains ----
            f32x16 sA, sB;
#pragma unroll
            for (int r = 0; r < 16; ++r) { sA[r] = 0.f; sB[r] = 0.f; }
            const u16* kbh = KH + cb * 4096 + l31 * 128;
            const u16* kbl = KL + cb * 2048 + l31 * 64;
            const int rs = l31 & 15, rs7 = l31 & 7;
            __builtin_amdgcn_s_setprio(1);
#pragma unroll
            for (int c = 0; c < 4; ++c) {
                bf16x8 fh = *(const bf16x8*)(kbh + ((g + 2 * c) ^ rs) * 8);
                bf16x8 fl = *(const bf16x8*)(kbl + ((g + 2 * c) ^ rs7) * 8);
                sA = MFMA32(fh, Qh[c], sA);
                sB = MFMA32(fl, Qh[c], sB);
                sB = MFMA32(fh, Qlv[c], sB);
            }
#pragma unroll
            for (int c = 4; c < 8; ++c) {
                bf16x8 fh = *(const bf16x8*)(kbh + ((g + 2 * c) ^ rs) * 8);
                sA = MFMA32(fh, Qh[c], sA);
            }
            __builtin_amdgcn_s_setprio(0);

            // ---- online softmax, base-2 ----
            float s[16];
#pragma unroll
            for (int r = 0; r < 16; ++r) s[r] = sA[r] + sB[r];
            float m01 = fmaxf(s[0], s[1]),   m23 = fmaxf(s[2], s[3]);
            float m45 = fmaxf(s[4], s[5]),   m67 = fmaxf(s[6], s[7]);
            float m89 = fmaxf(s[8], s[9]),   mab = fmaxf(s[10], s[11]);
            float mcd = fmaxf(s[12], s[13]), mef = fmaxf(s[14], s[15]);
            float mt = fmaxf(fmaxf(fmaxf(m01, m23), fmaxf(m45, m67)),
                             fmaxf(fmaxf(m89, mab), fmaxf(mcd, mef)));
            mt = fmaxf(mt, __shfl_xor(mt, 32));
            if (!__all(mt - m_run <= 11.54f)) {
                float mn = fmaxf(m_run, mt);
                float corr = __builtin_amdgcn_exp2f(m_run - mn);
                l_run *= corr;
#pragma unroll
                for (int r = 0; r < 16; ++r) { o0[r] *= corr; o1[r] *= corr; }
                m_run = mn;
            }
#pragma unroll
            for (int r = 0; r < 16; ++r) s[r] = __builtin_amdgcn_exp2f(s[r] - m_run);
            float p01 = s[0] + s[1],   p23 = s[2] + s[3];
            float p45 = s[4] + s[5],   p67 = s[6] + s[7];
            float p89 = s[8] + s[9],   pab = s[10] + s[11];
            float pcd = s[12] + s[13], pef = s[14] + s[15];
            float ps = ((p01 + p23) + (p45 + p67)) + ((p89 + pab) + (pcd + pef));
            ps += __shfl_xor(ps, 32);
            l_run += ps;

            // ---- P -> bf16 via v_perm truncation ----
            u32 pk[4], pk2[4];
#pragma unroll
            for (int e = 0; e < 4; ++e) {
                pk[e]  = __builtin_amdgcn_perm(__float_as_uint(s[2 * e + 1]),
                                               __float_as_uint(s[2 * e]), 0x07060302u);
                pk2[e] = __builtin_amdgcn_perm(__float_as_uint(s[8 + 2 * e + 1]),
                                               __float_as_uint(s[8 + 2 * e]), 0x07060302u);
            }
            bf16x8 ph0 = *(bf16x8*)pk;
            bf16x8 ph1 = *(bf16x8*)pk2;

            // ---- V fragments (pitch 40) ----
            const u16* vb = VH + cb * 2560;
            bf16x8 v00, v01, v10, v11;
            {
                const u16* p00 = vb + l31 * 40 + g * 4;
                const u16* p10 = vb + (32 + l31) * 40 + g * 4;
                bf16x4 a0 = *(const bf16x4*)(p00);      bf16x4 a1 = *(const bf16x4*)(p00 + 8);
                bf16x4 b0 = *(const bf16x4*)(p00 + 16); bf16x4 b1 = *(const bf16x4*)(p00 + 24);
                bf16x4 c0 = *(const bf16x4*)(p10);      bf16x4 c1 = *(const bf16x4*)(p10 + 8);
                bf16x4 d0 = *(const bf16x4*)(p10 + 16); bf16x4 d1 = *(const bf16x4*)(p10 + 24);
                v00 = __builtin_shufflevector(a0, a1, 0, 1, 2, 3, 4, 5, 6, 7);
                v01 = __builtin_shufflevector(b0, b1, 0, 1, 2, 3, 4, 5, 6, 7);
                v10 = __builtin_shufflevector(c0, c1, 0, 1, 2, 3, 4, 5, 6, 7);
                v11 = __builtin_shufflevector(d0, d1, 0, 1, 2, 3, 4, 5, 6, 7);
            }

            __builtin_amdgcn_s_setprio(1);
            o0 = MFMA32(v00, ph0, o0);
            o0 = MFMA32(v01, ph1, o0);
            o1 = MFMA32(v10, ph0, o1);
            o1 = MFMA32(v11, ph1, o1);
            __builtin_amdgcn_s_setprio(0);
        }

        __syncthreads();
    }

    // ---- epilogue: normalize and write final fp32 output ----
    float inv = 1.0f / l_run;
    float* op = out + qtok * 64;
#pragma unroll
    for (int sg = 0; sg < 4; ++sg) {
        *(float4*)(op + sg * 8 + g * 4) = make_float4(
            o0[4*sg+0]*inv, o0[4*sg+1]*inv, o0[4*sg+2]*inv, o0[4*sg+3]*inv);
        *(float4*)(op + 32 + sg * 8 + g * 4) = make_float4(
            o1[4*sg+0]*inv, o1[4*sg+1]*inv, o1[4*sg+2]*inv, o1[4*sg+3]*inv);
    }
#undef STAGEK
}

extern "C" void kernel_launch(void* const* d_in, const int* in_sizes, int n_in,
                              void* d_out, int out_size, void* d_ws, size_t ws_size,
                              hipStream_t stream) {
    const float* vectors = (const float*)d_in[0];
    const float* scalars = (const float*)d_in[1];
    const float* Wq   = (const float*)d_in[2];
    const float* Wq_s = (const float*)d_in[3];
    const float* bq_s = (const float*)d_in[4];
    const float* Wk   = (const float*)d_in[5];
    const float* Wk_s = (const float*)d_in[6];
    const float* bk_s = (const float*)d_in[7];
    const float* Wv   = (const float*)d_in[8];
    float* o = (float*)d_out;

    u16* qh  = (u16*)d_ws;                 // 65536*128
    u16* ql  = qh + 8388608;               // 65536*64
    u16* kh  = ql + 4194304;               // 65536*128
    u16* kl  = kh + 8388608;               // 65536*64
    u16* vth = kl + 4194304;               // 64*64*1024
    u16* gmh = vth + 4194304;              // 4096 each
    u16* gml = gmh + 4096;
    u16* mvh = gml + 4096;
    u16* mvl = mvh + 4096;

    g_kernel<<<8, 256, 0, stream>>>(Wq, Wk, Wv, gmh, gml, mvh, mvl);
    prep_kernel<<<2048, 256, 0, stream>>>(vectors, scalars, Wq_s, bq_s,
                                          Wk_s, bk_s, gmh, gml, mvh, mvl,
                                          qh, ql, kh, kl, vth);
    attn_kernel<<<512, 256, 0, stream>>>(qh, ql, kh, kl, vth, o);
}

// Round 23
// 92.468 us; speedup vs baseline: 1.0165x; 1.0165x over previous
//
#include <hip/hip_runtime.h>
#include <math.h>

typedef float f32x16 __attribute__((ext_vector_type(16)));
typedef short bf16x8 __attribute__((ext_vector_type(8)));
typedef short bf16x4 __attribute__((ext_vector_type(4)));
typedef unsigned short u16;
typedef unsigned int u32;

#define MFMA32(a, b, c) __builtin_amdgcn_mfma_f32_32x32x16_bf16(a, b, c, 0, 0, 0)

__device__ __forceinline__ u16 f2bf(float x) {
    u32 u = __float_as_uint(x);
    u += 0x7FFFu + ((u >> 16) & 1u);
    return (u16)(u >> 16);
}
__device__ __forceinline__ float bf2f(u16 h) {
    return __uint_as_float(((u32)h) << 16);
}
__device__ __forceinline__ void gload16(const void* g, void* l) {
    __builtin_amdgcn_global_load_lds(
        (const __attribute__((address_space(1))) unsigned int*)g,
        (__attribute__((address_space(3))) unsigned int*)l, 16, 0, 0);
}

// ---------------------------------------------------------------------------
// g_kernel: 64x64 component-block matrices, bf16 hi/lo planes.
// ---------------------------------------------------------------------------
__global__ __launch_bounds__(256) void g_kernel(
    const float* __restrict__ Wq, const float* __restrict__ Wk,
    const float* __restrict__ Wv,
    u16* __restrict__ gmh, u16* __restrict__ gml,
    u16* __restrict__ mvh, u16* __restrict__ mvl)
{
    const int bk = blockIdx.x;
    const int base = ((bk & 3) * 256 + threadIdx.x) * 4;
    if (bk < 4) {
#pragma unroll
        for (int i = 0; i < 4; ++i) {
            int e = base + i;
            int f = e >> 6, fp = e & 63;
            int c = f & 3, cp = fp & 3, j = f >> 2, jp = fp >> 2;
            float val = 0.f;
            if (c == cp) {
                float a0 = 0.f, a1 = 0.f;
#pragma unroll 8
                for (int ff = 0; ff < 32; ff += 2) {
                    a0 = fmaf(Wq[ff * 16 + j],       Wk[ff * 16 + jp],       a0);
                    a1 = fmaf(Wq[(ff + 1) * 16 + j], Wk[(ff + 1) * 16 + jp], a1);
                }
                val = (a0 + a1) * ((c == 0) ? 1.f : -1.f);
            }
            u16 h = f2bf(val);
            gmh[e] = h; gml[e] = f2bf(val - bf2f(h));
        }
    } else {
#pragma unroll
        for (int i = 0; i < 4; ++i) {
            int e = base + i;
            int f = e >> 6, fp = e & 63;
            float val = ((f & 3) == (fp & 3)) ? expf(Wv[(f >> 2) * 16 + (fp >> 2)]) : 0.f;
            u16 h = f2bf(val);
            mvh[e] = h; mvl[e] = f2bf(val - bf2f(h));
        }
    }
}

// ---------------------------------------------------------------------------
// prep v16: all-MFMA, zero LDS; q-side scale folds log2(e).
// ---------------------------------------------------------------------------
__global__ __launch_bounds__(256) void prep_kernel(
    const float* __restrict__ vectors, const float* __restrict__ scalars,
    const float* __restrict__ Wq_s, const float* __restrict__ bq_s,
    const float* __restrict__ Wk_s, const float* __restrict__ bk_s,
    const u16* __restrict__ gmh, const u16* __restrict__ gml,
    const u16* __restrict__ mvh, const u16* __restrict__ mvl,
    u16* __restrict__ qh, u16* __restrict__ ql,
    u16* __restrict__ kh, u16* __restrict__ kl,
    u16* __restrict__ vth)
{
    const int t = threadIdx.x;
    const int w = t >> 6;
    const int lane = t & 63;
    const int l31 = lane & 31, g = lane >> 5;
    const int b = blockIdx.x >> 5;
    const int n0 = (blockIdx.x & 31) << 5;
    const long tok0 = (long)b * 1024 + n0;
    const float SC2 = 0.07216878364870323f * 1.4426950408889634f;

    if (w == 1 || w == 2) {
        bf16x8 Ah[4], Al[4];
        const float* vrow = vectors + (tok0 + l31) * 64 + g * 8;
#pragma unroll
        for (int kk = 0; kk < 4; ++kk) {
            float4 x0 = *(const float4*)(vrow + kk * 16);
            float4 x1 = *(const float4*)(vrow + kk * 16 + 4);
            float nr0 = x0.x * x0.x - x0.y * x0.y - x0.z * x0.z - x0.w * x0.w;
            float iv0 = 1.0f / sqrtf(fmaxf(fabsf(nr0), 1e-5f));
            float nr1 = x1.x * x1.x - x1.y * x1.y - x1.z * x1.z - x1.w * x1.w;
            float iv1 = 1.0f / sqrtf(fmaxf(fabsf(nr1), 1e-5f));
            float xs[8] = {x0.x * iv0, x0.y * iv0, x0.z * iv0, x0.w * iv0,
                           x1.x * iv1, x1.y * iv1, x1.z * iv1, x1.w * iv1};
#pragma unroll
            for (int e = 0; e < 8; ++e) {
                u16 h = f2bf(xs[e]);
                Ah[kk][e] = (short)h;
                Al[kk][e] = (short)f2bf(xs[e] - bf2f(h));
            }
        }

        const u16* bhp = (w == 1) ? gmh : mvh;
        const u16* blp = (w == 1) ? gml : mvl;
#pragma unroll
        for (int tile = 0; tile < 2; ++tile) {
            const int fs = tile * 32 + l31;
            const u16* bh = bhp + fs * 64 + g * 8;
            const u16* bl = blp + fs * 64 + g * 8;
            f32x16 acc;
#pragma unroll
            for (int r = 0; r < 16; ++r) acc[r] = 0.f;
#pragma unroll
            for (int kk = 0; kk < 4; ++kk) {
                bf16x8 Bh = *(const bf16x8*)(bh + kk * 16);
                bf16x8 Bl = *(const bf16x8*)(bl + kk * 16);
                acc = MFMA32(Ah[kk], Bh, acc);
                acc = MFMA32(Al[kk], Bh, acc);
                acc = MFMA32(Ah[kk], Bl, acc);
            }
            if (w == 1) {
#pragma unroll
                for (int reg = 0; reg < 16; ++reg) {
                    int trow = (reg & 3) + 8 * (reg >> 2) + 4 * g;
                    float val = acc[reg];
                    u16 h = f2bf(val);
                    kh[(tok0 + trow) * 128 + fs] = h;
                    kl[(tok0 + trow) * 64 + fs] = f2bf(val - bf2f(h));
                }
            } else {
#pragma unroll
                for (int reg = 0; reg < 16; ++reg) {
                    int trow = (reg & 3) + 8 * (reg >> 2) + 4 * g;
                    vth[((long)b * 64 + fs) * 1024 + n0 + trow] = f2bf(acc[reg]);
                }
            }
        }
    } else {
        if (w == 0) {
            const float* vrow = vectors + (tok0 + l31) * 64 + g * 8;
#pragma unroll
            for (int kk = 0; kk < 4; ++kk) {
                float4 x0 = *(const float4*)(vrow + kk * 16);
                float4 x1 = *(const float4*)(vrow + kk * 16 + 4);
                float nr0 = x0.x * x0.x - x0.y * x0.y - x0.z * x0.z - x0.w * x0.w;
                float iv0 = SC2 / sqrtf(fmaxf(fabsf(nr0), 1e-5f));
                float nr1 = x1.x * x1.x - x1.y * x1.y - x1.z * x1.z - x1.w * x1.w;
                float iv1 = SC2 / sqrtf(fmaxf(fabsf(nr1), 1e-5f));
                float xs[8] = {x0.x * iv0, x0.y * iv0, x0.z * iv0, x0.w * iv0,
                               x1.x * iv1, x1.y * iv1, x1.z * iv1, x1.w * iv1};
                u16 hh[8], ll[8];
#pragma unroll
                for (int e = 0; e < 8; ++e) {
                    hh[e] = f2bf(xs[e]);
                    ll[e] = f2bf(xs[e] - bf2f(hh[e]));
                }
                *(int4*)(qh + (tok0 + l31) * 128 + kk * 16 + g * 8) = *(int4*)hh;
                *(int4*)(ql + (tok0 + l31) * 64 + kk * 16 + g * 8) = *(int4*)ll;
            }
        }
        const int isq = (w == 0);
        bf16x8 Ah[4];
        const float* xrow = scalars + (tok0 + l31) * 64 + g * 8;
#pragma unroll
        for (int kk = 0; kk < 4; ++kk) {
            float4 x0 = *(const float4*)(xrow + kk * 16);
            float4 x1 = *(const float4*)(xrow + kk * 16 + 4);
            float xs[8] = {x0.x, x0.y, x0.z, x0.w, x1.x, x1.y, x1.z, x1.w};
#pragma unroll
            for (int e = 0; e < 8; ++e) Ah[kk][e] = (short)f2bf(xs[e]);
        }
        const float sc = isq ? SC2 : 1.f;
        u16* oh = isq ? qh : kh;
#pragma unroll
        for (int ft = 0; ft < 2; ++ft) {
            const int fs = (ft << 5) + l31;
            const float* wrow = (isq ? Wq_s : Wk_s) + fs * 64 + g * 8;
            f32x16 acc;
#pragma unroll
            for (int r = 0; r < 16; ++r) acc[r] = 0.f;
#pragma unroll
            for (int kk = 0; kk < 4; ++kk) {
                float4 w0_ = *(const float4*)(wrow + kk * 16);
                float4 w1_ = *(const float4*)(wrow + kk * 16 + 4);
                float ws_[8] = {w0_.x, w0_.y, w0_.z, w0_.w, w1_.x, w1_.y, w1_.z, w1_.w};
                bf16x8 Bh;
#pragma unroll
                for (int e = 0; e < 8; ++e) Bh[e] = (short)f2bf(ws_[e]);
                acc = MFMA32(Ah[kk], Bh, acc);
            }
            const float bias = (isq ? bq_s : bk_s)[fs];
#pragma unroll
            for (int reg = 0; reg < 16; ++reg) {
                int trow = (reg & 3) + 8 * (reg >> 2) + 4 * g;
                oh[(tok0 + trow) * 128 + 64 + fs] = f2bf((acc[reg] + bias) * sc);
            }
        }
    }
}

// ---------------------------------------------------------------------------
// attn v18 (proven best): gload-K 2-buffer linear rows, V LDS pitch 40,
// 2-chain QK, exp2 softmax, v_perm P-pack, 512 blocks x 1024 keys,
// direct normalized fp32 output.
// ---------------------------------------------------------------------------
__global__ __launch_bounds__(256) void attn_kernel(
    const u16* __restrict__ qh, const u16* __restrict__ ql,
    const u16* __restrict__ kh, const u16* __restrict__ kl,
    const u16* __restrict__ vth, float* __restrict__ out)
{
    __shared__ u16 KH[2 * 32 * 128];   // 16 KB (gload, linear rows)
    __shared__ u16 KL[2 * 32 * 64];    //  8 KB (gload, linear rows)
    __shared__ u16 VH[2 * 64 * 40];    // 10 KB (ds_write, pitch 40)

    const int t = threadIdx.x;
    const int lane = t & 63;
    const int w = t >> 6;
    const int l31 = lane & 31, g = lane >> 5;

    const int bid = blockIdx.x;              // 0..511
    const int b = ((bid & 7) << 3) + (bid >> 6);
    const int qt = (bid >> 3) & 7;

    const int qi = qt * 128 + w * 32 + l31;
    const long qtok = (long)b * 1024 + qi;

    bf16x8 Qh[8], Qlv[4];
    {
        const u16* qhp = qh + qtok * 128 + g * 8;
        const u16* qlp = ql + qtok * 64 + g * 8;
#pragma unroll
        for (int c = 0; c < 8; ++c) Qh[c] = *(const bf16x8*)(qhp + c * 16);
#pragma unroll
        for (int c = 0; c < 4; ++c) Qlv[c] = *(const bf16x8*)(qlp + c * 16);
    }

    // K staging: pre-swizzled global sources, linear LDS dest
    const int r0 = 8 * w + (lane >> 4);
    const int r1 = r0 + 4;
    const int su0 = (lane & 15) ^ (r0 & 15);
    const int su1 = (lane & 15) ^ (r1 & 15);
    const u16* kh0 = kh + ((long)b * 1024 + r0) * 128 + su0 * 8;
    const u16* kh1 = kh + ((long)b * 1024 + r1) * 128 + su1 * 8;
    const int rl_ = 8 * w + (lane >> 3);
    const int sul = (lane & 7) ^ (rl_ & 7);
    const u16* kl0 = kl + ((long)b * 1024 + rl_) * 64 + sul * 8;

    // V staging: reg + ds_write, pitch 40
    const int vdv = t >> 2, vq4 = t & 3;
    const u16* vhg = vth + ((long)b * 64 + vdv) * 1024 + vq4 * 8;
    u16* vdst = VH + vdv * 40 + vq4 * 8;
    int4 rv0;

#define STAGEK(kt, bf) do { \
        gload16(kh0 + (long)(kt) * 128, KH + (bf) * 4096 + w * 1024); \
        gload16(kh1 + (long)(kt) * 128, KH + (bf) * 4096 + w * 1024 + 512); \
        gload16(kl0 + (long)(kt) * 64,  KL + (bf) * 2048 + w * 512); \
    } while (0)

    f32x16 o0, o1;
#pragma unroll
    for (int r = 0; r < 16; ++r) { o0[r] = 0.f; o1[r] = 0.f; }
    float m_run = -1e30f, l_run = 0.f;

    rv0 = *(const int4*)(vhg);
    STAGEK(0, 0);
    *(int4*)(vdst) = rv0;
    __syncthreads();

#pragma unroll 2
    for (int it = 0; it < 32; ++it) {
        const int cb = it & 1;
        if (it < 31) {
            rv0 = *(const int4*)(vhg + (it + 1) * 32);
            STAGEK((it + 1) * 32, cb ^ 1);
        }

        // ---- QK^T: 2 accumulator chains ----
        f32x16 sA, sB;
#pragma unroll
        for (int r = 0; r < 16; ++r) { sA[r] = 0.f; sB[r] = 0.f; }
        const u16* kbh = KH + cb * 4096 + l31 * 128;
        const u16* kbl = KL + cb * 2048 + l31 * 64;
        const int rs = l31 & 15, rs7 = l31 & 7;
        __builtin_amdgcn_s_setprio(1);
#pragma unroll
        for (int c = 0; c < 4; ++c) {
            bf16x8 fh = *(const bf16x8*)(kbh + ((g + 2 * c) ^ rs) * 8);
            bf16x8 fl = *(const bf16x8*)(kbl + ((g + 2 * c) ^ rs7) * 8);
            sA = MFMA32(fh, Qh[c], sA);
            sB = MFMA32(fl, Qh[c], sB);
            sB = MFMA32(fh, Qlv[c], sB);
        }
#pragma unroll
        for (int c = 4; c < 8; ++c) {
            bf16x8 fh = *(const bf16x8*)(kbh + ((g + 2 * c) ^ rs) * 8);
            sA = MFMA32(fh, Qh[c], sA);
        }
        __builtin_amdgcn_s_setprio(0);

        // ---- online softmax, base-2 ----
        float s[16];
#pragma unroll
        for (int r = 0; r < 16; ++r) s[r] = sA[r] + sB[r];
        float m01 = fmaxf(s[0], s[1]),   m23 = fmaxf(s[2], s[3]);
        float m45 = fmaxf(s[4], s[5]),   m67 = fmaxf(s[6], s[7]);
        float m89 = fmaxf(s[8], s[9]),   mab = fmaxf(s[10], s[11]);
        float mcd = fmaxf(s[12], s[13]), mef = fmaxf(s[14], s[15]);
        float mt = fmaxf(fmaxf(fmaxf(m01, m23), fmaxf(m45, m67)),
                         fmaxf(fmaxf(m89, mab), fmaxf(mcd, mef)));
        mt = fmaxf(mt, __shfl_xor(mt, 32));
        if (!__all(mt - m_run <= 11.54f)) {
            float mn = fmaxf(m_run, mt);
            float corr = __builtin_amdgcn_exp2f(m_run - mn);
            l_run *= corr;
#pragma unroll
            for (int r = 0; r < 16; ++r) { o0[r] *= corr; o1[r] *= corr; }
            m_run = mn;
        }
#pragma unroll
        for (int r = 0; r < 16; ++r) s[r] = __builtin_amdgcn_exp2f(s[r] - m_run);
        float p01 = s[0] + s[1],   p23 = s[2] + s[3];
        float p45 = s[4] + s[5],   p67 = s[6] + s[7];
        float p89 = s[8] + s[9],   pab = s[10] + s[11];
        float pcd = s[12] + s[13], pef = s[14] + s[15];
        float ps = ((p01 + p23) + (p45 + p67)) + ((p89 + pab) + (pcd + pef));
        ps += __shfl_xor(ps, 32);
        l_run += ps;

        // ---- P -> bf16 via v_perm truncation ----
        u32 pk[4], pk2[4];
#pragma unroll
        for (int e = 0; e < 4; ++e) {
            pk[e]  = __builtin_amdgcn_perm(__float_as_uint(s[2 * e + 1]),
                                           __float_as_uint(s[2 * e]), 0x07060302u);
            pk2[e] = __builtin_amdgcn_perm(__float_as_uint(s[8 + 2 * e + 1]),
                                           __float_as_uint(s[8 + 2 * e]), 0x07060302u);
        }
        bf16x8 ph0 = *(bf16x8*)pk;
        bf16x8 ph1 = *(bf16x8*)pk2;

        // ---- V fragments (pitch 40) ----
        const u16* vb = VH + cb * 2560;
        bf16x8 v00, v01, v10, v11;
        {
            const u16* p00 = vb + l31 * 40 + g * 4;
            const u16* p10 = vb + (32 + l31) * 40 + g * 4;
            bf16x4 a0 = *(const bf16x4*)(p00);      bf16x4 a1 = *(const bf16x4*)(p00 + 8);
            bf16x4 b0 = *(const bf16x4*)(p00 + 16); bf16x4 b1 = *(const bf16x4*)(p00 + 24);
            bf16x4 c0 = *(const bf16x4*)(p10);      bf16x4 c1 = *(const bf16x4*)(p10 + 8);
            bf16x4 d0 = *(const bf16x4*)(p10 + 16); bf16x4 d1 = *(const bf16x4*)(p10 + 24);
            v00 = __builtin_shufflevector(a0, a1, 0, 1, 2, 3, 4, 5, 6, 7);
            v01 = __builtin_shufflevector(b0, b1, 0, 1, 2, 3, 4, 5, 6, 7);
            v10 = __builtin_shufflevector(c0, c1, 0, 1, 2, 3, 4, 5, 6, 7);
            v11 = __builtin_shufflevector(d0, d1, 0, 1, 2, 3, 4, 5, 6, 7);
        }

        __builtin_amdgcn_s_setprio(1);
        o0 = MFMA32(v00, ph0, o0);
        o0 = MFMA32(v01, ph1, o0);
        o1 = MFMA32(v10, ph0, o1);
        o1 = MFMA32(v11, ph1, o1);
        __builtin_amdgcn_s_setprio(0);

        if (it < 31) *(int4*)(vdst + (cb ^ 1) * 2560) = rv0;
        __syncthreads();
    }

    // ---- epilogue: normalize and write final fp32 output ----
    float inv = 1.0f / l_run;
    float* op = out + qtok * 64;
#pragma unroll
    for (int sg = 0; sg < 4; ++sg) {
        *(float4*)(op + sg * 8 + g * 4) = make_float4(
            o0[4*sg+0]*inv, o0[4*sg+1]*inv, o0[4*sg+2]*inv, o0[4*sg+3]*inv);
        *(float4*)(op + 32 + sg * 8 + g * 4) = make_float4(
            o1[4*sg+0]*inv, o1[4*sg+1]*inv, o1[4*sg+2]*inv, o1[4*sg+3]*inv);
    }
#undef STAGEK
}

extern "C" void kernel_launch(void* const* d_in, const int* in_sizes, int n_in,
                              void* d_out, int out_size, void* d_ws, size_t ws_size,
                              hipStream_t stream) {
    const float* vectors = (const float*)d_in[0];
    const float* scalars = (const float*)d_in[1];
    const float* Wq   = (const float*)d_in[2];
    const float* Wq_s = (const float*)d_in[3];
    const float* bq_s = (const float*)d_in[4];
    const float* Wk   = (const float*)d_in[5];
    const float* Wk_s = (const float*)d_in[6];
    const float* bk_s = (const float*)d_in[7];
    const float* Wv   = (const float*)d_in[8];
    float* o = (float*)d_out;

    u16* qh  = (u16*)d_ws;                 // 65536*128
    u16* ql  = qh + 8388608;               // 65536*64
    u16* kh  = ql + 4194304;               // 65536*128
    u16* kl  = kh + 8388608;               // 65536*64
    u16* vth = kl + 4194304;               // 64*64*1024
    u16* gmh = vth + 4194304;              // 4096 each
    u16* gml = gmh + 4096;
    u16* mvh = gml + 4096;
    u16* mvl = mvh + 4096;

    g_kernel<<<8, 256, 0, stream>>>(Wq, Wk, Wv, gmh, gml, mvh, mvl);
    prep_kernel<<<2048, 256, 0, stream>>>(vectors, scalars, Wq_s, bq_s,
                                          Wk_s, bk_s, gmh, gml, mvh, mvl,
                                          qh, ql, kh, kl, vth);
    attn_kernel<<<512, 256, 0, stream>>>(qh, ql, kh, kl, vth, o);
}